// Round 4
// baseline (1333.974 us; speedup 1.0000x reference)
//
#include <hip/hip_runtime.h>
#include <hip/hip_bf16.h>

#define HIDDEN 64
#define TN 64           // nodes per tile in GEMM kernel
#define APAD 68         // tile row stride: rows 4 apart -> +16 banks, 8 apart -> 2-way (free)

// ---------------------------------------------------------------------------
// CSR build step 1: degree histogram over dst
// ---------------------------------------------------------------------------
__global__ __launch_bounds__(256) void k_hist(
    const int* __restrict__ ei, int* __restrict__ deg, int nEdges)
{
    for (int e = blockIdx.x * blockDim.x + threadIdx.x; e < nEdges;
         e += gridDim.x * blockDim.x) {
        atomicAdd(&deg[ei[nEdges + e]], 1);
    }
}

// ---------------------------------------------------------------------------
// CSR build step 2: exclusive scan deg -> rowPtr[0..n] and cursor copy
// ---------------------------------------------------------------------------
__global__ __launch_bounds__(1024) void k_scan(
    const int* __restrict__ deg, int* __restrict__ rowPtr,
    int* __restrict__ cursor, int n)
{
    __shared__ int part[1024];
    const int t = threadIdx.x;
    const int seg = (n + 1023) / 1024;
    const int beg = t * seg;
    const int end = min(beg + seg, n);
    int s = 0;
    for (int i = beg; i < end; ++i) s += deg[i];
    part[t] = s;
    __syncthreads();
    for (int off = 1; off < 1024; off <<= 1) {
        int v = (t >= off) ? part[t - off] : 0;
        __syncthreads();
        part[t] += v;
        __syncthreads();
    }
    int run = (t == 0) ? 0 : part[t - 1];   // exclusive prefix
    for (int i = beg; i < end; ++i) {
        const int d = deg[i];
        rowPtr[i] = run;
        cursor[i] = run;
        run += d;
    }
    if (beg < n && end == n) rowPtr[n] = run;
}

// ---------------------------------------------------------------------------
// CSR build step 3: fill (order within a node's list is arbitrary)
// ---------------------------------------------------------------------------
__global__ __launch_bounds__(256) void k_fill(
    const int* __restrict__ ei, int* __restrict__ cursor,
    int* __restrict__ csrSrc, int nEdges)
{
    for (int e = blockIdx.x * blockDim.x + threadIdx.x; e < nEdges;
         e += gridDim.x * blockDim.x) {
        const int dst = ei[nEdges + e];
        const int pos = atomicAdd(&cursor[dst], 1);
        csrSrc[pos] = ei[e];
    }
}

// ---------------------------------------------------------------------------
// Mean-aggregate: one 64-lane wave per node, lane = feature.
// Low VGPR by construction -> high occupancy; 8 gathers in flight per lane.
// ---------------------------------------------------------------------------
__global__ __launch_bounds__(256, 8) void k_agg(
    const float* __restrict__ xin,     // [N,64]
    const int* __restrict__ rowPtr,    // [N+1]
    const int* __restrict__ csrSrc,    // [E]
    float* __restrict__ mean,          // [N,64]
    int nNodes)
{
    const int node = blockIdx.x * 4 + (threadIdx.x >> 6);
    const int lane = threadIdx.x & 63;
    if (node >= nNodes) return;
    const int beg = rowPtr[node], end = rowPtr[node + 1];
    float a0 = 0.f, a1 = 0.f;
    int i = beg;
#pragma unroll 1
    for (; i + 7 < end; i += 8) {            // 8 loads in flight, 2 add chains
        const int s0 = csrSrc[i + 0], s1 = csrSrc[i + 1];
        const int s2 = csrSrc[i + 2], s3 = csrSrc[i + 3];
        const int s4 = csrSrc[i + 4], s5 = csrSrc[i + 5];
        const int s6 = csrSrc[i + 6], s7 = csrSrc[i + 7];
        a0 += xin[s0 * HIDDEN + lane] + xin[s1 * HIDDEN + lane]
            + xin[s2 * HIDDEN + lane] + xin[s3 * HIDDEN + lane];
        a1 += xin[s4 * HIDDEN + lane] + xin[s5 * HIDDEN + lane]
            + xin[s6 * HIDDEN + lane] + xin[s7 * HIDDEN + lane];
    }
#pragma unroll 1
    for (; i + 3 < end; i += 4) {
        const int s0 = csrSrc[i + 0], s1 = csrSrc[i + 1];
        const int s2 = csrSrc[i + 2], s3 = csrSrc[i + 3];
        a0 += xin[s0 * HIDDEN + lane] + xin[s1 * HIDDEN + lane];
        a1 += xin[s2 * HIDDEN + lane] + xin[s3 * HIDDEN + lane];
    }
#pragma unroll 1
    for (; i < end; ++i) a0 += xin[csrSrc[i] * HIDDEN + lane];
    const float inv = (end > beg) ? 1.0f / (float)(end - beg) : 1.0f;
    mean[node * HIDDEN + lane] = (a0 + a1) * inv;
}

// ---------------------------------------------------------------------------
// One GEMM K-pass over a staged 64x64 tile: acc += A[tr4+r][k] * B[k][tc4+j]
// ---------------------------------------------------------------------------
__device__ __forceinline__ void gemm_pass(
    const float (*sA)[APAD], const float (*sB)[HIDDEN],
    int tr, int tc, float acc[4][4])
{
#pragma unroll
    for (int k4 = 0; k4 < 16; ++k4) {
        float A_[4][4], B_[4][4];
#pragma unroll
        for (int r = 0; r < 4; ++r) {
            const float4 t4 = *(const float4*)&sA[tr * 4 + r][k4 * 4];
            A_[r][0] = t4.x; A_[r][1] = t4.y; A_[r][2] = t4.z; A_[r][3] = t4.w;
        }
#pragma unroll
        for (int kk = 0; kk < 4; ++kk) {
            const float4 t4 = *(const float4*)&sB[k4 * 4 + kk][tc * 4];
            B_[kk][0] = t4.x; B_[kk][1] = t4.y; B_[kk][2] = t4.z; B_[kk][3] = t4.w;
        }
#pragma unroll
        for (int kk = 0; kk < 4; ++kk)
#pragma unroll
            for (int r = 0; r < 4; ++r)
#pragma unroll
                for (int j = 0; j < 4; ++j)
                    acc[r][j] = fmaf(A_[r][kk], B_[kk][j], acc[r][j]);
    }
}

// ---------------------------------------------------------------------------
// Tile GEMM: out = mean @ Wl + bl + xin @ Wr   (optional ReLU)
// Stages mean/x tiles into LDS FIRST, syncs, then computes -> safe even when
// outp aliases mean (in-place layer-2: each block reads only rows it writes).
// ---------------------------------------------------------------------------
template <bool RELU>
__global__ __launch_bounds__(256, 3) void k_gemm(
    const float* __restrict__ mean,    // [N,64]
    const float* __restrict__ xin,     // [N,64]
    const float* __restrict__ Wl,      // [64,64]
    const float* __restrict__ bl,      // [64]
    const float* __restrict__ Wr,      // [64,64]
    float* __restrict__ outp,          // [N,64]  (may alias mean)
    int nNodes)
{
    __shared__ __align__(16) float sM[TN][APAD];
    __shared__ __align__(16) float sX[TN][APAD];
    __shared__ __align__(16) float sB[HIDDEN][HIDDEN];

    const int tr = threadIdx.x >> 4;     // 0..15 node group
    const int tc = threadIdx.x & 15;     // 0..15 col group
    const int base = blockIdx.x * TN;

    // stage Wl; consumed after first barrier
    for (int i = threadIdx.x; i < HIDDEN * HIDDEN; i += 256)
        sB[i >> 6][i & 63] = Wl[i];

    // stage mean & x tiles (float4 coalesced, 4 per thread per tile)
    for (int idx = threadIdx.x; idx < TN * 16; idx += 256) {
        const int row = idx >> 4, c4 = idx & 15;
        const int g = base + row;
        float4 m4 = make_float4(0.f, 0.f, 0.f, 0.f);
        float4 x4 = make_float4(0.f, 0.f, 0.f, 0.f);
        if (g < nNodes) {
            m4 = *(const float4*)&mean[g * HIDDEN + c4 * 4];
            x4 = *(const float4*)&xin[g * HIDDEN + c4 * 4];
        }
        *(float4*)&sM[row][c4 * 4] = m4;
        *(float4*)&sX[row][c4 * 4] = x4;
    }

    float bias[4];
#pragma unroll
    for (int j = 0; j < 4; ++j) bias[j] = bl[tc * 4 + j];

    __syncthreads();           // sM, sX, sB(Wl) ready

    float acc[4][4];
#pragma unroll
    for (int r = 0; r < 4; ++r)
#pragma unroll
        for (int j = 0; j < 4; ++j) acc[r][j] = bias[j];

    gemm_pass(sM, sB, tr, tc, acc);      // mean @ Wl

    __syncthreads();           // done reading sB(Wl)
    for (int i = threadIdx.x; i < HIDDEN * HIDDEN; i += 256)
        sB[i >> 6][i & 63] = Wr[i];
    __syncthreads();           // sB(Wr) ready

    gemm_pass(sX, sB, tr, tc, acc);      // + x @ Wr

#pragma unroll
    for (int r = 0; r < 4; ++r) {
        const int g = base + tr * 4 + r;
        if (g < nNodes) {
            float4 o;
            o.x = acc[r][0]; o.y = acc[r][1]; o.z = acc[r][2]; o.w = acc[r][3];
            if (RELU) {
                o.x = fmaxf(o.x, 0.f); o.y = fmaxf(o.y, 0.f);
                o.z = fmaxf(o.z, 0.f); o.w = fmaxf(o.w, 0.f);
            }
            *(float4*)&outp[g * HIDDEN + tc * 4] = o;
        }
    }
}

extern "C" void kernel_launch(void* const* d_in, const int* in_sizes, int n_in,
                              void* d_out, int out_size, void* d_ws, size_t ws_size,
                              hipStream_t stream)
{
    const float* x   = (const float*)d_in[0];
    const int*   ei  = (const int*)d_in[1];   // [2,E]
    const float* W1l = (const float*)d_in[2];
    const float* b1l = (const float*)d_in[3];
    const float* W1r = (const float*)d_in[4];
    const float* W2l = (const float*)d_in[5];
    const float* b2l = (const float*)d_in[6];
    const float* W2r = (const float*)d_in[7];
    float* out = (float*)d_out;

    const int nNodes = in_sizes[0] / HIDDEN;   // 100000
    const int nEdges = in_sizes[1] / 2;        // 1250000

    // workspace: h [N*64] f32 | deg [N+1] | rowPtr [N+1] | cursor [N] | csrSrc [E]
    // (mean buffer lives in d_out — reused as scratch; ws stays ~31 MB)
    float* h      = (float*)d_ws;
    int*   deg    = (int*)(h + (size_t)nNodes * HIDDEN);
    int*   rowPtr = deg + (nNodes + 1);
    int*   cursor = rowPtr + (nNodes + 1);
    int*   csrSrc = cursor + nNodes;

    const int nTiles = (nNodes + TN - 1) / TN;
    const int aggGrid = (nNodes + 3) / 4;

    // ---- CSR build (shared by both layers) ----
    hipMemsetAsync(deg, 0, (size_t)(nNodes + 1) * sizeof(int), stream);
    k_hist<<<2048, 256, 0, stream>>>(ei, deg, nEdges);
    k_scan<<<1, 1024, 0, stream>>>(deg, rowPtr, cursor, nNodes);
    k_fill<<<2048, 256, 0, stream>>>(ei, cursor, csrSrc, nEdges);

    // ---- layer 1: h = relu(mean(x) @ W1l + b1l + x @ W1r) ----
    k_agg<<<aggGrid, 256, 0, stream>>>(x, rowPtr, csrSrc, out, nNodes);
    k_gemm<true><<<nTiles, 256, 0, stream>>>(out, x, W1l, b1l, W1r, h, nNodes);

    // ---- layer 2: out = mean(h) @ W2l + b2l + h @ W2r  (in-place on d_out) ----
    k_agg<<<aggGrid, 256, 0, stream>>>(h, rowPtr, csrSrc, out, nNodes);
    k_gemm<false><<<nTiles, 256, 0, stream>>>(out, h, W2l, b2l, W2r, out, nNodes);
}

// Round 6
// 1191.902 us; speedup vs baseline: 1.1192x; 1.1192x over previous
//
#include <hip/hip_runtime.h>
#include <hip/hip_bf16.h>

#define HIDDEN 64
#define TN 64           // nodes per tile in fused kernel
#define APAD 132        // sA row stride (128+4): 16B-aligned, breaks power-of-2 bank stride

// ---------------------------------------------------------------------------
// CSR build step 1: degree histogram over dst
// ---------------------------------------------------------------------------
__global__ __launch_bounds__(256) void k_hist(
    const int* __restrict__ ei, int* __restrict__ deg, int nEdges)
{
    for (int e = blockIdx.x * blockDim.x + threadIdx.x; e < nEdges;
         e += gridDim.x * blockDim.x) {
        atomicAdd(&deg[ei[nEdges + e]], 1);
    }
}

// ---------------------------------------------------------------------------
// Two-level parallel exclusive scan:
//   scan1: per-256-chunk local exclusive scan -> rowPtr, chunk total -> blockSum
//   scan2: 1 block scans blockSum (<=512 entries) in place, writes rowPtr[n]
//   scan3: rowPtr[i] += blockSum[chunk]; cursor[i] = rowPtr[i]
// ---------------------------------------------------------------------------
__global__ __launch_bounds__(256) void k_scan1(
    const int* __restrict__ deg, int* __restrict__ rowPtr,
    int* __restrict__ blockSum, int n)
{
    __shared__ int tmp[256];
    const int t = threadIdx.x;
    const int i = blockIdx.x * 256 + t;
    const int v = (i < n) ? deg[i] : 0;
    tmp[t] = v;
    __syncthreads();
#pragma unroll
    for (int off = 1; off < 256; off <<= 1) {
        const int u = (t >= off) ? tmp[t - off] : 0;
        __syncthreads();
        tmp[t] += u;
        __syncthreads();
    }
    if (i < n) rowPtr[i] = tmp[t] - v;              // local exclusive
    if (t == 255) blockSum[blockIdx.x] = tmp[255];  // chunk total
}

__global__ __launch_bounds__(512) void k_scan2(
    int* __restrict__ blockSum, int* __restrict__ rowPtr, int nb, int n)
{
    __shared__ int tmp[512];
    const int t = threadIdx.x;
    const int v = (t < nb) ? blockSum[t] : 0;
    tmp[t] = v;
    __syncthreads();
#pragma unroll
    for (int off = 1; off < 512; off <<= 1) {
        const int u = (t >= off) ? tmp[t - off] : 0;
        __syncthreads();
        tmp[t] += u;
        __syncthreads();
    }
    if (t < nb) blockSum[t] = tmp[t] - v;           // exclusive chunk offset
    if (t == nb - 1) rowPtr[n] = tmp[t];            // total edges
}

__global__ __launch_bounds__(256) void k_scan3(
    int* __restrict__ rowPtr, int* __restrict__ cursor,
    const int* __restrict__ blockSum, int n)
{
    const int i = blockIdx.x * 256 + threadIdx.x;
    if (i < n) {
        const int v = rowPtr[i] + blockSum[blockIdx.x];
        rowPtr[i] = v;
        cursor[i] = v;
    }
}

// ---------------------------------------------------------------------------
// CSR build step 3: fill (order within a node's list is arbitrary)
// ---------------------------------------------------------------------------
__global__ __launch_bounds__(256) void k_fill(
    const int* __restrict__ ei, int* __restrict__ cursor,
    int* __restrict__ csrSrc, int nEdges)
{
    for (int e = blockIdx.x * blockDim.x + threadIdx.x; e < nEdges;
         e += gridDim.x * blockDim.x) {
        const int dst = ei[nEdges + e];
        const int pos = atomicAdd(&cursor[dst], 1);
        csrSrc[pos] = ei[e];
    }
}

// ---------------------------------------------------------------------------
// One GEMM K-pass: acc[r][j] += sA[tr*4+r][kOff+k] * sB[k][tc*4+j], k=0..63
// ---------------------------------------------------------------------------
__device__ __forceinline__ void gemm_pass(
    const float (*sA)[APAD], const float (*sB)[HIDDEN],
    int tr, int tc, int kOff, float acc[4][4])
{
#pragma unroll
    for (int k4 = 0; k4 < 16; ++k4) {
        float A_[4][4], B_[4][4];
#pragma unroll
        for (int r = 0; r < 4; ++r) {
            const float4 t4 = *(const float4*)&sA[tr * 4 + r][kOff + k4 * 4];
            A_[r][0] = t4.x; A_[r][1] = t4.y; A_[r][2] = t4.z; A_[r][3] = t4.w;
        }
#pragma unroll
        for (int kk = 0; kk < 4; ++kk) {
            const float4 t4 = *(const float4*)&sB[k4 * 4 + kk][tc * 4];
            B_[kk][0] = t4.x; B_[kk][1] = t4.y; B_[kk][2] = t4.z; B_[kk][3] = t4.w;
        }
#pragma unroll
        for (int kk = 0; kk < 4; ++kk)
#pragma unroll
            for (int r = 0; r < 4; ++r)
#pragma unroll
                for (int j = 0; j < 4; ++j)
                    acc[r][j] = fmaf(A_[r][kk], B_[kk][j], acc[r][j]);
    }
}

// ---------------------------------------------------------------------------
// Fused SAGE layer. Per 64-node tile:
//   phase 1: CSR mean-gather -> sA[node][0..63], root row -> sA[node][64..127]
//            node loop unroll=1 (ONE node state live -> low VGPR);
//            edge loop padded to 8-wide epochs with clamped idx + 0/1 mask
//            so ALL gathers go 8-deep in flight (no serial tail).
//   phase 2: out = sA[:,0:64]@Wl + bl + sA[:,64:128]@Wr  (sB reused Wl->Wr)
// 256 threads = 4 waves (agg) = 16x16 (GEMM 4x4/thread). LDS 50.2 KB -> 3/CU.
// ---------------------------------------------------------------------------
template <bool RELU>
__global__ __launch_bounds__(256, 3) void k_fused(
    const float* __restrict__ xin,     // [N,64]
    const int* __restrict__ rowPtr,    // [N+1]
    const int* __restrict__ csrSrc,    // [E]
    const float* __restrict__ Wl,      // [64,64]
    const float* __restrict__ bl,      // [64]
    const float* __restrict__ Wr,      // [64,64]
    float* __restrict__ outp,          // [N,64]
    int nNodes)
{
    __shared__ __align__(16) float sA[TN][APAD];
    __shared__ __align__(16) float sB[HIDDEN][HIDDEN];

    const int w    = threadIdx.x >> 6;   // wave 0..3
    const int lane = threadIdx.x & 63;
    const int tr   = threadIdx.x >> 4;   // 0..15 node group
    const int tc   = threadIdx.x & 15;   // 0..15 col group
    const int base = blockIdx.x * TN;

    // stage Wl; first consumed after the barrier below
    for (int i = threadIdx.x; i < HIDDEN * HIDDEN; i += 256)
        sB[i >> 6][i & 63] = Wl[i];

    // ---- phase 1: aggregation; wave w owns nodes w*16..w*16+15, ONE at a time
#pragma unroll 1
    for (int n = w * 16; n < w * 16 + 16; ++n) {
        const int g = base + n;
        float a0 = 0.f, a1 = 0.f, root = 0.f, inv = 1.f;
        if (g < nNodes) {
            const int beg = rowPtr[g], end = rowPtr[g + 1];
            if (end > beg) {
                const int last = end - 1;
#pragma unroll 1
                for (int i = beg; i < end; i += 8) {
                    // 8 clamped gathers in flight; invalid slots weighted 0
#pragma unroll
                    for (int k = 0; k < 8; k += 2) {
                        const int iA = i + k, iB = i + k + 1;
                        const int sA_ = csrSrc[min(iA, last)];
                        const int sB_ = csrSrc[min(iB, last)];
                        const float mA = (iA < end) ? 1.f : 0.f;
                        const float mB = (iB < end) ? 1.f : 0.f;
                        a0 = fmaf(mA, xin[sA_ * HIDDEN + lane], a0);
                        a1 = fmaf(mB, xin[sB_ * HIDDEN + lane], a1);
                    }
                }
                inv = 1.0f / (float)(end - beg);
            }
            root = xin[g * HIDDEN + lane];
        }
        sA[n][lane]      = (a0 + a1) * inv;
        sA[n][64 + lane] = root;
    }
    __syncthreads();            // sA complete AND sB(Wl) complete

    // ---- phase 2a: mean @ Wl ----
    float acc[4][4];
#pragma unroll
    for (int r = 0; r < 4; ++r)
#pragma unroll
        for (int j = 0; j < 4; ++j) acc[r][j] = bl[tc * 4 + j];
    gemm_pass(sA, sB, tr, tc, 0, acc);

    __syncthreads();            // done reading sB(Wl)
    for (int i = threadIdx.x; i < HIDDEN * HIDDEN; i += 256)
        sB[i >> 6][i & 63] = Wr[i];
    __syncthreads();            // sB(Wr) ready

    // ---- phase 2b: + root @ Wr ----
    gemm_pass(sA, sB, tr, tc, 64, acc);

    // ---- epilogue ----
#pragma unroll
    for (int r = 0; r < 4; ++r) {
        const int g = base + tr * 4 + r;
        if (g < nNodes) {
            float4 o;
            o.x = acc[r][0]; o.y = acc[r][1]; o.z = acc[r][2]; o.w = acc[r][3];
            if (RELU) {
                o.x = fmaxf(o.x, 0.f); o.y = fmaxf(o.y, 0.f);
                o.z = fmaxf(o.z, 0.f); o.w = fmaxf(o.w, 0.f);
            }
            *(float4*)&outp[g * HIDDEN + tc * 4] = o;
        }
    }
}

extern "C" void kernel_launch(void* const* d_in, const int* in_sizes, int n_in,
                              void* d_out, int out_size, void* d_ws, size_t ws_size,
                              hipStream_t stream)
{
    const float* x   = (const float*)d_in[0];
    const int*   ei  = (const int*)d_in[1];   // [2,E]
    const float* W1l = (const float*)d_in[2];
    const float* b1l = (const float*)d_in[3];
    const float* W1r = (const float*)d_in[4];
    const float* W2l = (const float*)d_in[5];
    const float* b2l = (const float*)d_in[6];
    const float* W2r = (const float*)d_in[7];
    float* out = (float*)d_out;

    const int nNodes = in_sizes[0] / HIDDEN;   // 100000
    const int nEdges = in_sizes[1] / 2;        // 1250000

    // workspace: h [N*64] | deg [N+1] | rowPtr [N+1] | cursor [N] | csrSrc [E]
    //            | blockSum [512]
    float* h        = (float*)d_ws;
    int*   deg      = (int*)(h + (size_t)nNodes * HIDDEN);
    int*   rowPtr   = deg + (nNodes + 1);
    int*   cursor   = rowPtr + (nNodes + 1);
    int*   csrSrc   = cursor + nNodes;
    int*   blockSum = csrSrc + nEdges;

    const int nTiles  = (nNodes + TN - 1) / TN;
    const int nChunks = (nNodes + 255) / 256;      // 391 for N=100000

    // ---- CSR build (shared by both layers) ----
    hipMemsetAsync(deg, 0, (size_t)(nNodes + 1) * sizeof(int), stream);
    k_hist<<<2048, 256, 0, stream>>>(ei, deg, nEdges);
    k_scan1<<<nChunks, 256, 0, stream>>>(deg, rowPtr, blockSum, nNodes);
    k_scan2<<<1, 512, 0, stream>>>(blockSum, rowPtr, nChunks, nNodes);
    k_scan3<<<nChunks, 256, 0, stream>>>(rowPtr, cursor, blockSum, nNodes);
    k_fill<<<2048, 256, 0, stream>>>(ei, cursor, csrSrc, nEdges);

    // ---- layer 1: h = relu(mean(x) @ W1l + b1l + x @ W1r) ----
    k_fused<true><<<nTiles, 256, 0, stream>>>(x, rowPtr, csrSrc, W1l, b1l, W1r,
                                              h, nNodes);
    // ---- layer 2: out = mean(h) @ W2l + b2l + h @ W2r ----
    k_fused<false><<<nTiles, 256, 0, stream>>>(h, rowPtr, csrSrc, W2l, b2l, W2r,
                                               out, nNodes);
}